// Round 4
// baseline (222.768 us; speedup 1.0000x reference)
//
#include <hip/hip_runtime.h>
#include <math.h>

// SEM_40200893890649: TopK_with_h + mat_GRU_cell + 2-layer GCN (fp32)
// R4: 4-kernel pipeline.
//   K1: redundant per-block scorer + chunk scores + chunk top-64 (grid 256)
//   K2: merge top-64 + policy/entropy + gather ne0T + gather+normalize A (grid 32)
//   K3: fused GRU (grid 32x4)
//   K4: whole GCN per batch (grid 32)

namespace {
constexpr int B_ = 32;
constexpr int N_ = 2000;
constexpr int D_ = 128;
constexpr int R_ = 640;

// ---------- workspace layout (float offsets) ----------
constexpr size_t OFF_CANDV = 0;        // [32][8][64]
constexpr size_t OFF_CANDI = 16384;    // int [32][8][64]
constexpr size_t OFF_STATS = 32768;    // [32][8][3]
constexpr size_t OFF_T0    = 33536;    // [32][64]
constexpr size_t OFF_NE0T  = 35584;    // [32][128][64]
constexpr size_t OFF_A0N   = 297728;   // [32][64][64] normalized (incl dup 2x)
constexpr size_t OFF_DW    = 428800;   // [32][128][128]
constexpr size_t OFF_H1    = 953088;   // [32][64][128]
// end 1215232 floats = 4.6 MiB

// =============== K1: scorer (redundant per block) + scores + chunk top-64 ===============
__global__ __launch_bounds__(256) void k1_score(
    const float* __restrict__ node, const float* __restrict__ ht,
    const float* __restrict__ mw, const float* __restrict__ mb,
    float* __restrict__ outScorer, float* __restrict__ cand_v,
    int* __restrict__ cand_i, float* __restrict__ stats) {
  const int blk = blockIdx.x, t = threadIdx.x;
  const int b = blk >> 3, c = blk & 7;
  const int lane = t & 63, w = t >> 6;
  __shared__ float sh[R_];
  __shared__ float part[2][128];
  __shared__ float sc[D_];
  __shared__ float red[2];
  __shared__ float cv[256];
  __shared__ int ci[256];
  __shared__ float r1[4], r2[4];
  // scorer = tanh(ht[b] @ mw^T + mb), computed redundantly by each block
  for (int j = t; j < R_; j += 256) sh[j] = ht[b * R_ + j];
  __syncthreads();
  {
    const int d = t & 127, half = t >> 7;
    const float* wp = mw + (size_t)d * R_ + half * 320;
    const float* hh = sh + half * 320;
    float acc = 0.f;
    for (int j = 0; j < 320; j += 4) {
      float4 wv = *reinterpret_cast<const float4*>(wp + j);
      acc += wv.x * hh[j] + wv.y * hh[j + 1] + wv.z * hh[j + 2] + wv.w * hh[j + 3];
    }
    part[half][d] = acc;
  }
  __syncthreads();
  if (t < 128) {
    const float s = tanhf(part[0][t] + part[1][t] + mb[t]);
    sc[t] = s;
    if (c == 0) outScorer[b * D_ + t] = s;
    float ss = s * s;
    #pragma unroll
    for (int o = 32; o > 0; o >>= 1) ss += __shfl_down(ss, o);
    if ((t & 63) == 0) red[t >> 6] = ss;
  }
  __syncthreads();
  const float inv = 1.0f / sqrtf(red[0] + red[1]);
  // scores for this 250-row chunk
  const int n = c * 250 + t;
  const bool valid = t < 250;
  float v = -INFINITY;
  if (valid) {
    const float* row = node + ((size_t)b * N_ + n) * D_;
    float acc = 0.f;
    for (int j = 0; j < D_; j += 4) {
      float4 a = *reinterpret_cast<const float4*>(row + j);
      acc += a.x * sc[j] + a.y * sc[j + 1] + a.z * sc[j + 2] + a.w * sc[j + 3];
    }
    v = acc * inv;
  }
  // chunk max
  float m = v;
  #pragma unroll
  for (int o = 32; o > 0; o >>= 1) m = fmaxf(m, __shfl_xor(m, o));
  if (lane == 0) r1[w] = m;
  __syncthreads();
  const float Mc = fmaxf(fmaxf(r1[0], r1[1]), fmaxf(r1[2], r1[3]));
  __syncthreads();
  // chunk softmax partials
  float se = 0.f, sx = 0.f;
  if (valid) {
    const float x = v - Mc;
    const float e = expf(x);
    se = e;
    sx = x * e;
  }
  #pragma unroll
  for (int o = 32; o > 0; o >>= 1) {
    se += __shfl_xor(se, o);
    sx += __shfl_xor(sx, o);
  }
  if (lane == 0) { r1[w] = se; r2[w] = sx; }
  cv[t] = v;
  ci[t] = valid ? n : 0x7fffffff;
  __syncthreads();
  if (t == 0) {
    float* st = stats + ((size_t)b * 8 + c) * 3;
    st[0] = Mc;
    st[1] = r1[0] + r1[1] + r1[2] + r1[3];
    st[2] = r2[0] + r2[1] + r2[2] + r2[3];
  }
  // rank-select chunk top-64 (value desc, index asc = lax.top_k order)
  const float mv = cv[t];
  const int mi = ci[t];
  int rank = 0;
  for (int j = 0; j < 256; ++j) {
    const float jv = cv[j];
    const int ji = ci[j];
    rank += (jv > mv || (jv == mv && ji < mi)) ? 1 : 0;
  }
  if (valid && rank < 64) {
    cand_v[((size_t)b * 8 + c) * 64 + rank] = mv;
    cand_i[((size_t)b * 8 + c) * 64 + rank] = mi;
  }
}

// =============== K2: merge + policy/entropy + gather ne0T + gather/normalize A ===============
__global__ __launch_bounds__(256) void k2_merge_gather(
    const float* __restrict__ cand_v, const int* __restrict__ cand_i,
    const float* __restrict__ stats, const float* __restrict__ node,
    const float* __restrict__ Ahat, float* __restrict__ t0v,
    float* __restrict__ outPolicy, float* __restrict__ outEntropy,
    float* __restrict__ ne0T, float* __restrict__ A0n) {
  const int b = blockIdx.x, t = threadIdx.x;
  __shared__ float cv[512];
  __shared__ int ci[512];
  __shared__ float sv[64];
  __shared__ int si[64];
  __shared__ float Ar[64][65];
  __shared__ float lne[64][132];
  __shared__ float di[64];
  cv[t] = cand_v[(size_t)b * 512 + t];
  ci[t] = cand_i[(size_t)b * 512 + t];
  cv[256 + t] = cand_v[(size_t)b * 512 + 256 + t];
  ci[256 + t] = cand_i[(size_t)b * 512 + 256 + t];
  __syncthreads();
  #pragma unroll
  for (int e = 0; e < 2; ++e) {
    const float mv = cv[t + e * 256];
    const int mi = ci[t + e * 256];
    int rank = 0;
    for (int j = 0; j < 512; ++j) {
      const float jv = cv[j];
      const int ji = ci[j];
      rank += (jv > mv || (jv == mv && ji < mi)) ? 1 : 0;
    }
    if (rank < 64) { sv[rank] = mv; si[rank] = mi; }
  }
  __syncthreads();
  if (t < 64) {
    const float v = sv[t];
    t0v[b * 64 + t] = tanhf(v);
    float s = v;
    #pragma unroll
    for (int o = 32; o > 0; o >>= 1) s += __shfl_xor(s, o);
    if (t == 0) {
      float M = -INFINITY;
      for (int c = 0; c < 8; ++c) M = fmaxf(M, stats[((size_t)b * 8 + c) * 3]);
      float se = 0.f, sx = 0.f;
      for (int c = 0; c < 8; ++c) {
        const float* st = stats + ((size_t)b * 8 + c) * 3;
        const float f = expf(st[0] - M);
        se += f * st[1];
        sx += f * (st[2] + (st[0] - M) * st[1]);
      }
      const float logS = logf(se);
      outPolicy[b] = s * (1.0f / 64.0f) - M - logS;
      outEntropy[b] = logS - sx / se;
    }
  }
  __syncthreads();
  // gather node rows -> lne, and A[si[i]][si[j]] -> Ar
  {
    const int k = t >> 2, q = t & 3;
    const float* src = node + ((size_t)b * N_ + si[k]) * D_ + q * 32;
    #pragma unroll
    for (int j = 0; j < 32; j += 4)
      *reinterpret_cast<float4*>(&lne[k][q * 32 + j]) =
          *reinterpret_cast<const float4*>(src + j);
  }
  {
    const int j = t & 63;
    const int cj = si[j];
    const int i0 = (t >> 6) * 16;
    const float* Ab = Ahat + (size_t)b * N_ * N_;
    #pragma unroll
    for (int s = 0; s < 16; ++s) {
      const int i = i0 + s;
      Ar[i][j] = Ab[(size_t)si[i] * N_ + cj];
    }
  }
  __syncthreads();
  // ne0T write (transpose of lne)
  {
    const int f = t >> 1, kh = (t & 1) * 32;
    float* dst = ne0T + ((size_t)b * D_ + f) * 64 + kh;
    #pragma unroll
    for (int j = 0; j < 32; j += 4) {
      float4 v;
      v.x = lne[kh + j][f];
      v.y = lne[kh + j + 1][f];
      v.z = lne[kh + j + 2][f];
      v.w = lne[kh + j + 3][f];
      *reinterpret_cast<float4*>(dst + j) = v;
    }
  }
  // degree normalize: di = (2*colsum)^-1/2; An = 2*di_i*di_j*Ar (dup 2x folded)
  if (t < 64) {
    float s = 0.f;
    #pragma unroll
    for (int i = 0; i < 64; ++i) s += Ar[i][t];
    di[t] = 1.0f / sqrtf(2.0f * s);
  }
  __syncthreads();
  {
    const int i = t >> 2, j0 = (t & 3) * 16;
    const float sI = 2.0f * di[i];
    float* dst = A0n + ((size_t)b * 64 + i) * 64;
    #pragma unroll
    for (int j4 = 0; j4 < 16; j4 += 4) {
      float4 o;
      o.x = Ar[i][j0 + j4]     * sI * di[j0 + j4];
      o.y = Ar[i][j0 + j4 + 1] * sI * di[j0 + j4 + 1];
      o.z = Ar[i][j0 + j4 + 2] * sI * di[j0 + j4 + 2];
      o.w = Ar[i][j0 + j4 + 3] * sI * di[j0 + j4 + 3];
      *reinterpret_cast<float4*>(dst + j0 + j4) = o;
    }
  }
}

// =============== K3: fused GRU (proven in R2) ===============
__global__ __launch_bounds__(256) void k3_gru(
    const float* __restrict__ Wu, const float* __restrict__ Uu, const float* __restrict__ bu,
    const float* __restrict__ Wr, const float* __restrict__ Ur, const float* __restrict__ br,
    const float* __restrict__ Wh, const float* __restrict__ Uh, const float* __restrict__ bh,
    const float* __restrict__ ne0T, const float* __restrict__ t0v,
    const float* __restrict__ P, float* __restrict__ Dw) {
  const int b = blockIdx.x, c = blockIdx.y;
  const int t = threadIdx.x, tx = t & 15, ty = t >> 4;
  __shared__ float Wt[16][132], Ut[16][132];
  __shared__ float Xt[16][36], Yt[16][36];
  __shared__ float gs[2][128][33];
  __shared__ float t0s[32];
  if (t < 32) t0s[t] = t0v[b * 64 + (c & 1) * 32 + t];
  const float* neT = ne0T + (size_t)b * D_ * 64;
  const float* Pb = P + (size_t)b * D_ * D_;
  for (int z = 0; z < 2; ++z) {
    const float* W = z ? Wr : Wu;
    const float* U = z ? Ur : Uu;
    const float* bb = z ? br : bu;
    float acc[8][2] = {};
    for (int f0 = 0; f0 < D_; f0 += 16) {
      __syncthreads();
      #pragma unroll
      for (int rr = 0; rr < 8; rr++) {
        const int i = rr * 16 + ty;
        Wt[tx][i] = W[i * D_ + f0 + tx];
        Ut[tx][i] = U[i * D_ + f0 + tx];
      }
      {
        const int ff = ty, kk = tx * 2;
        Xt[ff][kk]     = neT[(f0 + ff) * 64 + (c & 1) * 32 + kk] * t0s[kk];
        Xt[ff][kk + 1] = neT[(f0 + ff) * 64 + (c & 1) * 32 + kk + 1] * t0s[kk + 1];
        const float2 p2 = *reinterpret_cast<const float2*>(Pb + (f0 + ff) * D_ + c * 32 + kk);
        Yt[ff][kk] = p2.x;
        Yt[ff][kk + 1] = p2.y;
      }
      __syncthreads();
      #pragma unroll
      for (int ff = 0; ff < 16; ff++) {
        const float xv0 = Xt[ff][tx * 2], xv1 = Xt[ff][tx * 2 + 1];
        const float yv0 = Yt[ff][tx * 2], yv1 = Yt[ff][tx * 2 + 1];
        const float4 wa = *reinterpret_cast<const float4*>(&Wt[ff][ty * 8]);
        const float4 wb = *reinterpret_cast<const float4*>(&Wt[ff][ty * 8 + 4]);
        const float4 ua = *reinterpret_cast<const float4*>(&Ut[ff][ty * 8]);
        const float4 ub = *reinterpret_cast<const float4*>(&Ut[ff][ty * 8 + 4]);
        const float wv[8] = {wa.x, wa.y, wa.z, wa.w, wb.x, wb.y, wb.z, wb.w};
        const float uv[8] = {ua.x, ua.y, ua.z, ua.w, ub.x, ub.y, ub.z, ub.w};
        #pragma unroll
        for (int r = 0; r < 8; r++) {
          acc[r][0] += wv[r] * xv0 + uv[r] * yv0;
          acc[r][1] += wv[r] * xv1 + uv[r] * yv1;
        }
      }
    }
    #pragma unroll
    for (int r = 0; r < 8; r++) {
      const int i = ty * 8 + r;
      #pragma unroll
      for (int cc = 0; cc < 2; cc++) {
        const int kk = tx * 2 + cc;
        const float zz = acc[r][cc] + bb[i * D_ + c * 32 + kk];
        gs[z][i][kk] = 1.f / (1.f + expf(-zz));
      }
    }
  }
  float acc[8][2] = {};
  for (int f0 = 0; f0 < D_; f0 += 16) {
    __syncthreads();
    #pragma unroll
    for (int rr = 0; rr < 8; rr++) {
      const int i = rr * 16 + ty;
      Wt[tx][i] = Wh[i * D_ + f0 + tx];
      Ut[tx][i] = Uh[i * D_ + f0 + tx];
    }
    {
      const int ff = ty, kk = tx * 2;
      Xt[ff][kk]     = neT[(f0 + ff) * 64 + (c & 1) * 32 + kk] * t0s[kk];
      Xt[ff][kk + 1] = neT[(f0 + ff) * 64 + (c & 1) * 32 + kk + 1] * t0s[kk + 1];
      const float2 p2 = *reinterpret_cast<const float2*>(Pb + (f0 + ff) * D_ + c * 32 + kk);
      Yt[ff][kk]     = gs[1][f0 + ff][kk] * p2.x;
      Yt[ff][kk + 1] = gs[1][f0 + ff][kk + 1] * p2.y;
    }
    __syncthreads();
    #pragma unroll
    for (int ff = 0; ff < 16; ff++) {
      const float xv0 = Xt[ff][tx * 2], xv1 = Xt[ff][tx * 2 + 1];
      const float yv0 = Yt[ff][tx * 2], yv1 = Yt[ff][tx * 2 + 1];
      const float4 wa = *reinterpret_cast<const float4*>(&Wt[ff][ty * 8]);
      const float4 wb = *reinterpret_cast<const float4*>(&Wt[ff][ty * 8 + 4]);
      const float4 ua = *reinterpret_cast<const float4*>(&Ut[ff][ty * 8]);
      const float4 ub = *reinterpret_cast<const float4*>(&Ut[ff][ty * 8 + 4]);
      const float wv[8] = {wa.x, wa.y, wa.z, wa.w, wb.x, wb.y, wb.z, wb.w};
      const float uv[8] = {ua.x, ua.y, ua.z, ua.w, ub.x, ub.y, ub.z, ub.w};
      #pragma unroll
      for (int r = 0; r < 8; r++) {
        acc[r][0] += wv[r] * xv0 + uv[r] * yv0;
        acc[r][1] += wv[r] * xv1 + uv[r] * yv1;
      }
    }
  }
  #pragma unroll
  for (int r = 0; r < 8; r++) {
    const int i = ty * 8 + r;
    #pragma unroll
    for (int cc = 0; cc < 2; cc++) {
      const int kk = tx * 2 + cc;
      const int k = c * 32 + kk;
      const size_t off = ((size_t)b * D_ + i) * D_ + k;
      const float hh = tanhf(acc[r][cc] + bh[i * D_ + k]);
      const float uu = gs[0][i][kk];
      const float pp = Pb[i * D_ + k];
      Dw[off] = (1.f - uu) * pp + uu * hh;
    }
  }
}

// =============== K4: whole GCN per batch ===============
// t1 = ne0 @ Dw; h1 = relu(An @ t1); t2 = h1 @ sw; h2 = relu(An @ t2);
// out = 0.5*(h1+h2), rows duplicated. An (normalized, 2x folded) from A0n.
__global__ __launch_bounds__(256) void k4_gcn(
    const float* __restrict__ ne0T, const float* __restrict__ Dw,
    const float* __restrict__ A0n, const float* __restrict__ sw,
    float* __restrict__ h1ws, float* __restrict__ out) {
  const int b = blockIdx.x, t = threadIdx.x;
  const int tx = t & 15, ty = t >> 4;
  __shared__ float As[64][68];
  __shared__ union {
    struct { float At[16][68]; float Bt[16][68]; } st;
    float Ts[64][68];
  } Un;
  const float* Ab = A0n + (size_t)b * 4096;
  const float* neT = ne0T + (size_t)b * D_ * 64;
  const float* Db = Dw + (size_t)b * D_ * D_;
  float* h1b = h1ws + (size_t)b * 64 * D_;
  #pragma unroll
  for (int ph = 0; ph < 4; ++ph) {
    const int i = ph * 16 + ty;
    *reinterpret_cast<float4*>(&As[i][tx * 4]) =
        *reinterpret_cast<const float4*>(Ab + i * 64 + tx * 4);
  }
  // ---- layer 1, per 64-col half ----
  for (int c = 0; c < 2; ++c) {
    float acc[4][4] = {};
    for (int f0 = 0; f0 < D_; f0 += 16) {
      __syncthreads();
      {
        const int ff = t >> 4, i4 = (t & 15) * 4;
        *reinterpret_cast<float4*>(&Un.st.At[ff][i4]) =
            *reinterpret_cast<const float4*>(neT + (f0 + ff) * 64 + i4);
        *reinterpret_cast<float4*>(&Un.st.Bt[ff][i4]) =
            *reinterpret_cast<const float4*>(Db + (f0 + ff) * D_ + c * 64 + i4);
      }
      __syncthreads();
      #pragma unroll
      for (int ff = 0; ff < 16; ff++) {
        const float4 av = *reinterpret_cast<const float4*>(&Un.st.At[ff][ty * 4]);
        const float4 bv = *reinterpret_cast<const float4*>(&Un.st.Bt[ff][tx * 4]);
        const float a_[4] = {av.x, av.y, av.z, av.w};
        const float b_[4] = {bv.x, bv.y, bv.z, bv.w};
        #pragma unroll
        for (int r = 0; r < 4; r++)
          #pragma unroll
          for (int cc = 0; cc < 4; cc++) acc[r][cc] += a_[r] * b_[cc];
      }
    }
    __syncthreads();
    #pragma unroll
    for (int r = 0; r < 4; r++) {
      float4 o = {acc[r][0], acc[r][1], acc[r][2], acc[r][3]};
      *reinterpret_cast<float4*>(&Un.Ts[ty * 4 + r][tx * 4]) = o;
    }
    __syncthreads();
    float acc2[4][4] = {};
    for (int ff = 0; ff < 64; ++ff) {
      const float4 bv = *reinterpret_cast<const float4*>(&Un.Ts[ff][tx * 4]);
      const float b_[4] = {bv.x, bv.y, bv.z, bv.w};
      #pragma unroll
      for (int r = 0; r < 4; r++) {
        const float a = As[ty * 4 + r][ff];
        #pragma unroll
        for (int cc = 0; cc < 4; cc++) acc2[r][cc] += a * b_[cc];
      }
    }
    #pragma unroll
    for (int r = 0; r < 4; r++) {
      float4 o = {fmaxf(acc2[r][0], 0.f), fmaxf(acc2[r][1], 0.f),
                  fmaxf(acc2[r][2], 0.f), fmaxf(acc2[r][3], 0.f)};
      *reinterpret_cast<float4*>(h1b + (ty * 4 + r) * D_ + c * 64 + tx * 4) = o;
    }
  }
  // ---- layer 2, per 64-col half ----
  for (int c = 0; c < 2; ++c) {
    float acc[4][4] = {};
    for (int f0 = 0; f0 < D_; f0 += 16) {
      __syncthreads();
      {
        const int ff = t >> 4, i4 = (t & 15) * 4;
        #pragma unroll
        for (int s = 0; s < 4; ++s)
          Un.st.At[ff][i4 + s] = h1b[(i4 + s) * D_ + f0 + ff];
        *reinterpret_cast<float4*>(&Un.st.Bt[ff][i4]) =
            *reinterpret_cast<const float4*>(sw + (f0 + ff) * D_ + c * 64 + i4);
      }
      __syncthreads();
      #pragma unroll
      for (int ff = 0; ff < 16; ff++) {
        const float4 av = *reinterpret_cast<const float4*>(&Un.st.At[ff][ty * 4]);
        const float4 bv = *reinterpret_cast<const float4*>(&Un.st.Bt[ff][tx * 4]);
        const float a_[4] = {av.x, av.y, av.z, av.w};
        const float b_[4] = {bv.x, bv.y, bv.z, bv.w};
        #pragma unroll
        for (int r = 0; r < 4; r++)
          #pragma unroll
          for (int cc = 0; cc < 4; cc++) acc[r][cc] += a_[r] * b_[cc];
      }
    }
    __syncthreads();
    #pragma unroll
    for (int r = 0; r < 4; r++) {
      float4 o = {acc[r][0], acc[r][1], acc[r][2], acc[r][3]};
      *reinterpret_cast<float4*>(&Un.Ts[ty * 4 + r][tx * 4]) = o;
    }
    __syncthreads();
    float acc2[4][4] = {};
    for (int ff = 0; ff < 64; ++ff) {
      const float4 bv = *reinterpret_cast<const float4*>(&Un.Ts[ff][tx * 4]);
      const float b_[4] = {bv.x, bv.y, bv.z, bv.w};
      #pragma unroll
      for (int r = 0; r < 4; r++) {
        const float a = As[ty * 4 + r][ff];
        #pragma unroll
        for (int cc = 0; cc < 4; cc++) acc2[r][cc] += a * b_[cc];
      }
    }
    #pragma unroll
    for (int r = 0; r < 4; r++) {
      const int i = ty * 4 + r;
      const int k = c * 64 + tx * 4;
      const float4 h1v = *reinterpret_cast<const float4*>(h1b + i * D_ + k);
      float4 o;
      o.x = 0.5f * (h1v.x + fmaxf(acc2[r][0], 0.f));
      o.y = 0.5f * (h1v.y + fmaxf(acc2[r][1], 0.f));
      o.z = 0.5f * (h1v.z + fmaxf(acc2[r][2], 0.f));
      o.w = 0.5f * (h1v.w + fmaxf(acc2[r][3], 0.f));
      *reinterpret_cast<float4*>(out + ((size_t)b * D_ + i) * D_ + k) = o;
      *reinterpret_cast<float4*>(out + ((size_t)b * D_ + i + 64) * D_ + k) = o;
    }
  }
}

}  // namespace

extern "C" void kernel_launch(void* const* d_in, const int* in_sizes, int n_in,
                              void* d_out, int out_size, void* d_ws, size_t ws_size,
                              hipStream_t stream) {
  (void)in_sizes; (void)n_in; (void)out_size; (void)ws_size;
  const float* Ahat = (const float*)d_in[0];
  const float* node = (const float*)d_in[1];
  const float* ht   = (const float*)d_in[2];
  const float* prevD= (const float*)d_in[3];
  const float* mw   = (const float*)d_in[4];
  const float* mb   = (const float*)d_in[5];
  const float* Wu   = (const float*)d_in[6];
  const float* Uu   = (const float*)d_in[7];
  const float* bu   = (const float*)d_in[8];
  const float* Wr   = (const float*)d_in[9];
  const float* Ur   = (const float*)d_in[10];
  const float* br   = (const float*)d_in[11];
  const float* Wh   = (const float*)d_in[12];
  const float* Uh   = (const float*)d_in[13];
  const float* bh   = (const float*)d_in[14];
  const float* sw   = (const float*)d_in[15];

  float* out = (float*)d_out;
  float* outPolicy  = out + (size_t)B_ * D_ * D_;
  float* outScorer  = outPolicy + B_;
  float* outEntropy = outScorer + (size_t)B_ * D_;

  float* ws = (float*)d_ws;
  float* cand_v = ws + OFF_CANDV;
  int*   cand_i = (int*)(ws + OFF_CANDI);
  float* stats  = ws + OFF_STATS;
  float* t0v    = ws + OFF_T0;
  float* ne0T   = ws + OFF_NE0T;
  float* A0n    = ws + OFF_A0N;
  float* Dw     = ws + OFF_DW;
  float* h1ws   = ws + OFF_H1;

  k1_score<<<256, 256, 0, stream>>>(node, ht, mw, mb, outScorer, cand_v, cand_i, stats);
  k2_merge_gather<<<B_, 256, 0, stream>>>(cand_v, cand_i, stats, node, Ahat,
                                          t0v, outPolicy, outEntropy, ne0T, A0n);
  k3_gru<<<dim3(B_, 4), 256, 0, stream>>>(Wu, Uu, bu, Wr, Ur, br, Wh, Uh, bh,
                                          ne0T, t0v, prevD, Dw);
  k4_gcn<<<B_, 256, 0, stream>>>(ne0T, Dw, A0n, sw, h1ws, out);
}